// Round 8
// baseline (509.172 us; speedup 1.0000x reference)
//
#include <hip/hip_runtime.h>
#include <hip/hip_bf16.h>
#include <math.h>

// ---------------------------------------------------------------------------
// ChebNet (K=3) two-layer forward, restructured:
//   cheb(x,W) = x@W0 - x@W2 + P(x@W1 + 2*P(x@W2)) + b,  P = edge scatter-sum
// P applied in output feature space (64 then 40 dims).
// Edge scatter -> CSR-by-dst gather (hierarchical scan build).
// k_count/k_fill: x4 edge unroll for atomic/scatter latency hiding.
// Layer-1 props (F=64): gather table SPLIT into two 6.4MB halves; two edge
//   passes per prop (per-pass working set fits L2 better). Quad-edge gathers.
// Layer-2 props (F=40): dual-edge single-table form (round-7).
// GEMM1: fp32 A via bf16 hi/lo split (3 MFMA); GEMM2: bf16 A exact (2 MFMA).
// ---------------------------------------------------------------------------

#define FIN1 128
#define HID 64
#define NCLS 40

typedef __attribute__((ext_vector_type(8))) short sx8;
typedef __attribute__((ext_vector_type(4))) float fx4;

__device__ inline unsigned short f2bf(float f) {
    unsigned u = __float_as_uint(f);
    unsigned r = (u + 0x7FFF + ((u >> 16) & 1)) >> 16;  // RNE
    return (unsigned short)r;
}
__device__ inline float bf2f(unsigned short h) {
    return __uint_as_float((unsigned)h << 16);
}
__device__ inline unsigned pack2bf(float a, float b) {
    return (unsigned)f2bf(a) | ((unsigned)f2bf(b) << 16);
}
__device__ inline float lo2f(unsigned v) { return __uint_as_float(v << 16); }
__device__ inline float hi2f(unsigned v) { return __uint_as_float(v & 0xffff0000u); }

__global__ void k_count(const int* __restrict__ dst, int E, int* __restrict__ count) {
    int g = blockIdx.x * blockDim.x + threadIdx.x;
    int e0 = g * 4;
    if (e0 >= E) return;
    if (e0 + 3 < E) {
        int4 d = ((const int4*)dst)[g];
        atomicAdd(&count[d.x], 1);
        atomicAdd(&count[d.y], 1);
        atomicAdd(&count[d.z], 1);
        atomicAdd(&count[d.w], 1);
    } else {
        for (int e = e0; e < E; ++e) atomicAdd(&count[dst[e]], 1);
    }
}

// ---- hierarchical exclusive scan over count[N] ----
template <int EPT>
__global__ __launch_bounds__(256) void k_scan_part(const int* __restrict__ count, int N,
                                                   int* __restrict__ partial) {
    __shared__ int ws[4];
    int t = threadIdx.x;
    int lane = t & 63, w = t >> 6;
    int idx0 = blockIdx.x * 256 * EPT + t * EPT;
    int s = 0;
#pragma unroll
    for (int i = 0; i < EPT; ++i) {
        int idx = idx0 + i;
        if (idx < N) s += count[idx];
    }
#pragma unroll
    for (int d = 1; d < 64; d <<= 1) s += __shfl_xor(s, d);
    if (lane == 0) ws[w] = s;
    __syncthreads();
    if (t == 0) partial[blockIdx.x] = ws[0] + ws[1] + ws[2] + ws[3];
}

__global__ __launch_bounds__(256) void k_scan_mid(int* __restrict__ partial, int nb) {
    __shared__ int s[256];
    int t = threadIdx.x;
    int orig = (t < nb) ? partial[t] : 0;
    s[t] = orig;
    __syncthreads();
    for (int d = 1; d < 256; d <<= 1) {
        int v = (t >= d) ? s[t - d] : 0;
        __syncthreads();
        s[t] += v;
        __syncthreads();
    }
    if (t < nb) partial[t] = s[t] - orig;  // exclusive
}

template <int EPT>
__global__ __launch_bounds__(256) void k_scan_final(const int* __restrict__ count, int N,
                                                    const int* __restrict__ partial,
                                                    int* __restrict__ row_ptr,
                                                    int* __restrict__ cursor,
                                                    float* __restrict__ dis) {
    __shared__ int wsum[4];
    int t = threadIdx.x;
    int lane = t & 63, w = t >> 6;
    int idx0 = blockIdx.x * 256 * EPT + t * EPT;
    int c[EPT];
    int s = 0;
#pragma unroll
    for (int i = 0; i < EPT; ++i) {
        int idx = idx0 + i;
        c[i] = (idx < N) ? count[idx] : 0;
        s += c[i];
    }
    int incl = s;
#pragma unroll
    for (int d = 1; d < 64; d <<= 1) {
        int u = __shfl_up(incl, d);
        if (lane >= d) incl += u;
    }
    if (lane == 63) wsum[w] = incl;
    __syncthreads();
    int woff = 0;
    for (int i = 0; i < w; ++i) woff += wsum[i];
    int off = partial[blockIdx.x] + woff + (incl - s);
#pragma unroll
    for (int i = 0; i < EPT; ++i) {
        int idx = idx0 + i;
        if (idx < N) {
            row_ptr[idx] = off;
            cursor[idx] = off;
            dis[idx] = (c[i] > 0) ? rsqrtf((float)c[i]) : 0.0f;
            off += c[i];
            if (idx == N - 1) row_ptr[N] = off;
        }
    }
}

__global__ void k_fill(const int* __restrict__ src, const int* __restrict__ dst, int E,
                       const float* __restrict__ dis, int* __restrict__ cursor,
                       int2* __restrict__ csrp) {
    int g = blockIdx.x * blockDim.x + threadIdx.x;
    int e0 = g * 4;
    if (e0 >= E) return;
    if (e0 + 3 < E) {
        int4 s4 = ((const int4*)src)[g];
        int4 d4 = ((const int4*)dst)[g];
        int ss[4] = {s4.x, s4.y, s4.z, s4.w};
        int dd[4] = {d4.x, d4.y, d4.z, d4.w};
        float nw[4];
#pragma unroll
        for (int i = 0; i < 4; ++i) nw[i] = -dis[ss[i]] * dis[dd[i]];
        int pos[4];
#pragma unroll
        for (int i = 0; i < 4; ++i) pos[i] = atomicAdd(&cursor[dd[i]], 1);
#pragma unroll
        for (int i = 0; i < 4; ++i)
            csrp[pos[i]] = make_int2(ss[i], __float_as_int(nw[i]));
    } else {
        for (int e = e0; e < E; ++e) {
            int s = src[e], d = dst[e];
            int pos = atomicAdd(&cursor[d], 1);
            csrp[pos] = make_int2(s, __float_as_int(-dis[s] * dis[d]));
        }
    }
}

// Pre-swizzle W[3][FIN][FOE] (fp32) into MFMA B-fragment layout, hi/lo bf16.
template <int NS, int T, int FIN, int FOE>
__global__ void k_wprep(const float* __restrict__ W, unsigned short* __restrict__ hi,
                        unsigned short* __restrict__ lo) {
    int idx = blockIdx.x * 256 + threadIdx.x;
    constexpr int total = NS * T * 64 * 8;
    if (idx >= total) return;
    int i = idx & 7;
    int l = (idx >> 3) & 63;
    int t = (idx >> 9) % T;
    int s = idx / (512 * T);
    int k = s * 32 + (l >> 4) * 8 + i;
    int col = t * 16 + (l & 15);
    float w = 0.0f;
    if (col < 3 * FOE) {
        int m = col / FOE;
        int c = col - m * FOE;
        w = W[((size_t)m * FIN + k) * FOE + c];
    }
    unsigned short h = f2bf(w);
    hi[idx] = h;
    lo[idx] = f2bf(w - bf2f(h));
}

// MFMA GEMM layer-1, fp32 A (hi/lo split, 3 MFMA): C{0,1,2} = A@W[m] (fp32);
// C2 additionally as SPLIT packed bf16: T0h (feat 0-31, 32 ushort/row),
// T1h (feat 32-63, 32 ushort/row).
template <int FIN, int T, int NS, int FOE>
__global__ __launch_bounds__(256, 3) void k_gemm_mfma(
    const float* __restrict__ A, const unsigned short* __restrict__ Whi,
    const unsigned short* __restrict__ Wlo, float* __restrict__ C0,
    float* __restrict__ C1, float* __restrict__ C2,
    unsigned short* __restrict__ T0h, unsigned short* __restrict__ T1h, int N) {
    int tid = threadIdx.x;
    int w = tid >> 6, l = tid & 63;
    int row0 = blockIdx.x * 128 + w * 32;
    int rl = l & 15, kg = l >> 4;

    fx4 acc[2][T];
#pragma unroll
    for (int rt = 0; rt < 2; ++rt)
#pragma unroll
        for (int t = 0; t < T; ++t) acc[rt][t] = (fx4)0.0f;

    for (int s = 0; s < NS; ++s) {
        int k0 = s * 32 + kg * 8;
        sx8 ahi[2], alo[2];
#pragma unroll
        for (int rt = 0; rt < 2; ++rt) {
            int r = min(row0 + rt * 16 + rl, N - 1);
            const fx4* ap = (const fx4*)(A + (size_t)r * FIN + k0);
            fx4 a0 = ap[0];
            fx4 a1 = ap[1];
#pragma unroll
            for (int j = 0; j < 4; ++j) {
                unsigned short h0 = f2bf(a0[j]);
                unsigned short h1 = f2bf(a1[j]);
                ahi[rt][j] = (short)h0;
                ahi[rt][j + 4] = (short)h1;
                alo[rt][j] = (short)f2bf(a0[j] - bf2f(h0));
                alo[rt][j + 4] = (short)f2bf(a1[j] - bf2f(h1));
            }
        }
        const sx8* wh = (const sx8*)(Whi + ((size_t)(s * T) * 64 + l) * 8);
        const sx8* wl = (const sx8*)(Wlo + ((size_t)(s * T) * 64 + l) * 8);
#pragma unroll
        for (int t = 0; t < T; ++t) {
            sx8 bh = wh[t * 64];
            sx8 bl = wl[t * 64];
#pragma unroll
            for (int rt = 0; rt < 2; ++rt) {
                acc[rt][t] = __builtin_amdgcn_mfma_f32_16x16x32_bf16(ahi[rt], bh, acc[rt][t], 0, 0, 0);
                acc[rt][t] = __builtin_amdgcn_mfma_f32_16x16x32_bf16(ahi[rt], bl, acc[rt][t], 0, 0, 0);
                acc[rt][t] = __builtin_amdgcn_mfma_f32_16x16x32_bf16(alo[rt], bh, acc[rt][t], 0, 0, 0);
            }
        }
    }

#pragma unroll
    for (int rt = 0; rt < 2; ++rt)
#pragma unroll
        for (int t = 0; t < T; ++t) {
            int col = t * 16 + rl;
            int m = col / FOE;
            int cc = col - m * FOE;
            if (m < 3) {
                float* Cm = (m == 0) ? C0 : ((m == 1) ? C1 : C2);
#pragma unroll
                for (int j = 0; j < 4; ++j) {
                    int r = row0 + rt * 16 + kg * 4 + j;
                    if (r < N) {
                        Cm[(size_t)r * FOE + cc] = acc[rt][t][j];
                        if (m == 2) {
                            unsigned short v = f2bf(acc[rt][t][j]);
                            if (cc < 32) T0h[(size_t)r * 32 + cc] = v;
                            else         T1h[(size_t)r * 32 + cc - 32] = v;
                        }
                    }
                }
            }
        }
}

// MFMA GEMM layer-2, bf16 A (exact, 2 MFMA): C{0,1,2} = A@W[m] (fp32);
// C2 additionally packed bf16 unsplit (ushort stride 64).
template <int FIN, int T, int NS, int FOE>
__global__ __launch_bounds__(256, 3) void k_gemm_mfma_bf(
    const unsigned short* __restrict__ A, const unsigned short* __restrict__ Whi,
    const unsigned short* __restrict__ Wlo, float* __restrict__ C0,
    float* __restrict__ C1, float* __restrict__ C2,
    unsigned short* __restrict__ C2h, int N) {
    int tid = threadIdx.x;
    int w = tid >> 6, l = tid & 63;
    int row0 = blockIdx.x * 128 + w * 32;
    int rl = l & 15, kg = l >> 4;

    fx4 acc[2][T];
#pragma unroll
    for (int rt = 0; rt < 2; ++rt)
#pragma unroll
        for (int t = 0; t < T; ++t) acc[rt][t] = (fx4)0.0f;

    for (int s = 0; s < NS; ++s) {
        int k0 = s * 32 + kg * 8;
        sx8 a[2];
#pragma unroll
        for (int rt = 0; rt < 2; ++rt) {
            int r = min(row0 + rt * 16 + rl, N - 1);
            a[rt] = *(const sx8*)(A + (size_t)r * FIN + k0);
        }
        const sx8* wh = (const sx8*)(Whi + ((size_t)(s * T) * 64 + l) * 8);
        const sx8* wl = (const sx8*)(Wlo + ((size_t)(s * T) * 64 + l) * 8);
#pragma unroll
        for (int t = 0; t < T; ++t) {
            sx8 bh = wh[t * 64];
            sx8 bl = wl[t * 64];
#pragma unroll
            for (int rt = 0; rt < 2; ++rt) {
                acc[rt][t] = __builtin_amdgcn_mfma_f32_16x16x32_bf16(a[rt], bh, acc[rt][t], 0, 0, 0);
                acc[rt][t] = __builtin_amdgcn_mfma_f32_16x16x32_bf16(a[rt], bl, acc[rt][t], 0, 0, 0);
            }
        }
    }

#pragma unroll
    for (int rt = 0; rt < 2; ++rt)
#pragma unroll
        for (int t = 0; t < T; ++t) {
            int col = t * 16 + rl;
            int m = col / FOE;
            int cc = col - m * FOE;
            if (m < 3) {
                float* Cm = (m == 0) ? C0 : ((m == 1) ? C1 : C2);
#pragma unroll
                for (int j = 0; j < 4; ++j) {
                    int r = row0 + rt * 16 + kg * 4 + j;
                    if (r < N) {
                        Cm[(size_t)r * FOE + cc] = acc[rt][t][j];
                        if (m == 2) C2h[(size_t)r * 64 + cc] = f2bf(acc[rt][t][j]);
                    }
                }
            }
        }
}

// Layer-1 CSR gather-prop, SPLIT-table two-pass form. One wave per dst node.
// Tables t0/t1: 16 dwords (32 bf16 feats) per row. Quad-edge gathers:
// q = lane>>4 picks edge within group-of-4, c = lane&15 the feature dword.
// Pass 0 touches only t0 (6.4MB), pass 1 only t1 -> better L2 residency.
// MODE 0: out split (o0 fp32): out0/out1[wid*16+c] = packbf16(o0 + 2*acc)
// MODE 1: out unsplit [wid*32+d]: relu(o0 - o1 + acc + bias)
template <int MODE>
__global__ void k_prop64(const int* __restrict__ row_ptr, const int2* __restrict__ csrp,
                         const unsigned* __restrict__ t0, const unsigned* __restrict__ t1,
                         const float* __restrict__ o0, const float* __restrict__ o1,
                         const float* __restrict__ bias,
                         unsigned* __restrict__ out0, unsigned* __restrict__ out1, int N) {
    int wid = (blockIdx.x * blockDim.x + threadIdx.x) >> 6;
    int lane = threadIdx.x & 63;
    if (wid >= N) return;
    int q = lane >> 4;
    int c = lane & 15;
    int beg = row_ptr[wid];
    int end = row_ptr[wid + 1];

    float a0x = 0.0f, a0y = 0.0f, a1x = 0.0f, a1y = 0.0f;
    // pass 0: table half 0
    for (int j = beg; j < end; j += 16) {
        int2 md = csrp[j + (lane & 15)];
#pragma unroll
        for (int t = 0; t < 4; ++t) {
            int idx = 4 * t + q;
            int s = __shfl(md.x, idx);
            float w = (j + idx < end) ? __int_as_float(__shfl(md.y, idx)) : 0.0f;
            unsigned v = t0[(size_t)s * 16 + c];
            a0x = fmaf(w, lo2f(v), a0x);
            a0y = fmaf(w, hi2f(v), a0y);
        }
    }
    // pass 1: table half 1
    for (int j = beg; j < end; j += 16) {
        int2 md = csrp[j + (lane & 15)];
#pragma unroll
        for (int t = 0; t < 4; ++t) {
            int idx = 4 * t + q;
            int s = __shfl(md.x, idx);
            float w = (j + idx < end) ? __int_as_float(__shfl(md.y, idx)) : 0.0f;
            unsigned v = t1[(size_t)s * 16 + c];
            a1x = fmaf(w, lo2f(v), a1x);
            a1y = fmaf(w, hi2f(v), a1y);
        }
    }
    // reduce over the 4 q-groups
    a0x += __shfl_xor(a0x, 16); a0x += __shfl_xor(a0x, 32);
    a0y += __shfl_xor(a0y, 16); a0y += __shfl_xor(a0y, 32);
    a1x += __shfl_xor(a1x, 16); a1x += __shfl_xor(a1x, 32);
    a1y += __shfl_xor(a1y, 16); a1y += __shfl_xor(a1y, 32);

    if (q != 0) return;
    // lane c holds feature pairs (2c,2c+1) [half0] and (32+2c,32+2c+1) [half1]
    float2 oa = ((const float2*)o0)[(size_t)wid * 32 + c];
    float2 ob = ((const float2*)o0)[(size_t)wid * 32 + 16 + c];
    if (MODE == 0) {
        out0[(size_t)wid * 16 + c] = pack2bf(oa.x + 2.0f * a0x, oa.y + 2.0f * a0y);
        out1[(size_t)wid * 16 + c] = pack2bf(ob.x + 2.0f * a1x, ob.y + 2.0f * a1y);
    } else {
        float2 qa = ((const float2*)o1)[(size_t)wid * 32 + c];
        float2 qb = ((const float2*)o1)[(size_t)wid * 32 + 16 + c];
        float2 ba = ((const float2*)bias)[c];
        float2 bb = ((const float2*)bias)[16 + c];
        float h0 = fmaxf(oa.x - qa.x + a0x + ba.x, 0.0f);
        float h1 = fmaxf(oa.y - qa.y + a0y + ba.y, 0.0f);
        float h2 = fmaxf(ob.x - qb.x + a1x + bb.x, 0.0f);
        float h3 = fmaxf(ob.y - qb.y + a1y + bb.y, 0.0f);
        out0[(size_t)wid * 32 + c] = pack2bf(h0, h1);
        out0[(size_t)wid * 32 + 16 + c] = pack2bf(h2, h3);
    }
}

// Layer-2 CSR gather-prop, dual-edge single-table (round-7 form). F=40.
// MODE 0: outh = packbf16(o0 + 2*acc)
// MODE 2: outf = log_softmax(o0 - o1 + acc + bias) over F classes (fp32)
template <int F, int MODE>
__global__ void k_prop(const int* __restrict__ row_ptr, const int2* __restrict__ csrp,
                       const unsigned* __restrict__ in,
                       const float* __restrict__ o0, const float* __restrict__ o1,
                       const float* __restrict__ bias,
                       unsigned* __restrict__ outh, float* __restrict__ outf, int N) {
    constexpr int FH = F / 2;
    int wid = (blockIdx.x * blockDim.x + threadIdx.x) >> 6;
    int lane = threadIdx.x & 63;
    if (wid >= N) return;
    int g = lane >> 5;   // edge slot within a pair
    int c = lane & 31;   // feature-pair index
    int beg = row_ptr[wid];
    int end = row_ptr[wid + 1];
    float ax = 0.0f, ay = 0.0f;
    for (int j = beg; j < end; j += 16) {
        int2 md = csrp[j + (lane & 15)];  // 16-edge metadata chunk, coalesced
#pragma unroll
        for (int t = 0; t < 8; ++t) {
            int idx = 2 * t + g;
            int s = __shfl(md.x, idx);
            float w = (j + idx < end) ? __int_as_float(__shfl(md.y, idx)) : 0.0f;
            unsigned v = in[(size_t)s * 32 + c];
            ax = fmaf(w, lo2f(v), ax);
            ay = fmaf(w, hi2f(v), ay);
        }
    }
    ax += __shfl_xor(ax, 32);
    ay += __shfl_xor(ay, 32);

    if (MODE == 0) {
        if (g == 0 && c < FH) {
            float2 o = ((const float2*)o0)[(size_t)wid * FH + c];
            outh[(size_t)wid * 32 + c] = pack2bf(o.x + 2.0f * ax, o.y + 2.0f * ay);
        }
    } else {
        float z0 = -INFINITY, z1 = -INFINITY;
        if (g == 0 && c < FH) {
            float2 o = ((const float2*)o0)[(size_t)wid * FH + c];
            float2 qq = ((const float2*)o1)[(size_t)wid * FH + c];
            float2 b = ((const float2*)bias)[c];
            z0 = o.x - qq.x + ax + b.x;
            z1 = o.y - qq.y + ay + b.y;
        }
        float m = fmaxf(z0, z1);
#pragma unroll
        for (int d = 32; d; d >>= 1) m = fmaxf(m, __shfl_xor(m, d));
        float e0 = (g == 0 && c < FH) ? expf(z0 - m) : 0.0f;
        float e1 = (g == 0 && c < FH) ? expf(z1 - m) : 0.0f;
        float l = e0 + e1;
#pragma unroll
        for (int d = 32; d; d >>= 1) l += __shfl_xor(l, d);
        if (g == 0 && c < FH) {
            float lg = m + logf(l);
            ((float2*)outf)[(size_t)wid * FH + c] = make_float2(z0 - lg, z1 - lg);
        }
    }
}

extern "C" void kernel_launch(void* const* d_in, const int* in_sizes, int n_in,
                              void* d_out, int out_size, void* d_ws, size_t ws_size,
                              hipStream_t stream) {
    const float* x = (const float*)d_in[0];
    const int* ei = (const int*)d_in[1];
    const float* W1 = (const float*)d_in[2];
    const float* b1 = (const float*)d_in[3];
    const float* W2 = (const float*)d_in[4];
    const float* b2 = (const float*)d_in[5];
    float* out = (float*)d_out;

    const int N = in_sizes[0] / FIN1;  // 100000
    const int E = in_sizes[1] / 2;     // 1600000
    const int* src = ei;
    const int* dst = ei + E;

    // workspace carve (256B aligned)
    char* p = (char*)d_ws;
    auto alloc = [&](size_t bytes) -> void* {
        void* r = (void*)p;
        p += (bytes + 255) & ~(size_t)255;
        return r;
    };
    int* count = (int*)alloc((size_t)N * 4);
    int* row_ptr = (int*)alloc((size_t)(N + 1) * 4);
    int* cursor = (int*)alloc((size_t)N * 4);
    float* dis = (float*)alloc((size_t)N * 4);
    int* partial = (int*)alloc(256 * 4);
    int2* csrp = (int2*)alloc(((size_t)E + 16) * 8);  // packed (src, norm) + pad
    float* buf0 = (float*)alloc((size_t)N * HID * 4);  // c0 / d0 (fp32)
    float* buf1 = (float*)alloc((size_t)N * HID * 4);  // ca / da (fp32)
    float* buf2 = (float*)alloc((size_t)N * HID * 4);  // cb / db (fp32)
    // blkA: layer-1 cb split tables; reused as layer-2 db table (buf2h)
    unsigned* blkA = (unsigned*)alloc((size_t)N * 32 * 4);
    unsigned* CB0 = blkA;                 // cb feats 0-31 (16 dwords/row)
    unsigned* CB1 = blkA + (size_t)N * 16;  // cb feats 32-63
    unsigned* buf2h = blkA;               // layer-2 db packed (32 dwords/row)
    // blkB: layer-1 s split tables; reused as layer-2 s2 table (buf3h)
    unsigned* blkB = (unsigned*)alloc((size_t)N * 32 * 4);
    unsigned* S0 = blkB;
    unsigned* S1 = blkB + (size_t)N * 16;
    unsigned* buf3h = blkB;
    unsigned* buf4h = (unsigned*)alloc((size_t)N * 32 * 4);  // h packed bf16x2
    // W fragment buffers (hi/lo bf16, B-frag layout)
    constexpr int W1FRAG = 4 * 12 * 64 * 8;  // 24576
    constexpr int W2FRAG = 2 * 8 * 64 * 8;   // 8192
    unsigned short* wf1h = (unsigned short*)alloc((size_t)W1FRAG * 2);
    unsigned short* wf1l = (unsigned short*)alloc((size_t)W1FRAG * 2);
    unsigned short* wf2h = (unsigned short*)alloc((size_t)W2FRAG * 2);
    unsigned short* wf2l = (unsigned short*)alloc((size_t)W2FRAG * 2);

    const int be4 = ((E + 3) / 4 + 255) / 256;  // x4-unrolled edge kernels
    const int bg = (N + 127) / 128;       // MFMA gemm blocks (BM=128)
    const int bp = (N * 64 + 255) / 256;  // one wave per node
    constexpr int EPB = 256 * 8;
    const int nb = (N + EPB - 1) / EPB;   // 49 blocks for N=100000

    // ---- W fragment prep (independent of graph) ----
    k_wprep<4, 12, FIN1, HID><<<(W1FRAG + 255) / 256, 256, 0, stream>>>(W1, wf1h, wf1l);
    k_wprep<2, 8, HID, NCLS><<<(W2FRAG + 255) / 256, 256, 0, stream>>>(W2, wf2h, wf2l);

    // ---- graph structure: degree, CSR, norm ----
    hipMemsetAsync(count, 0, (size_t)N * 4, stream);
    hipMemsetAsync(csrp + E, 0, (size_t)16 * 8, stream);  // zero pad records
    k_count<<<be4, 256, 0, stream>>>(dst, E, count);
    k_scan_part<8><<<nb, 256, 0, stream>>>(count, N, partial);
    k_scan_mid<<<1, 256, 0, stream>>>(partial, nb);
    k_scan_final<8><<<nb, 256, 0, stream>>>(count, N, partial, row_ptr, cursor, dis);
    k_fill<<<be4, 256, 0, stream>>>(src, dst, E, dis, cursor, csrp);

    // ---- layer 1: x[N,128] -> h[N,64] ----
    k_gemm_mfma<FIN1, 12, 4, HID><<<bg, 256, 0, stream>>>(
        x, wf1h, wf1l, buf0, buf1, buf2, (unsigned short*)CB0, (unsigned short*)CB1, N);
    // s = ca + 2*P(cb)  (split in, split out)
    k_prop64<0><<<bp, 256, 0, stream>>>(row_ptr, csrp, CB0, CB1, buf1, nullptr, nullptr,
                                        S0, S1, N);
    // h = relu(c0 - cb + P(s) + b1)  (split in, unsplit out for GEMM2)
    k_prop64<1><<<bp, 256, 0, stream>>>(row_ptr, csrp, S0, S1, buf0, buf2, b1,
                                        buf4h, nullptr, N);

    // ---- layer 2: h[N,64] -> out[N,40] ----
    k_gemm_mfma_bf<HID, 8, 2, NCLS><<<bg, 256, 0, stream>>>(
        (const unsigned short*)buf4h, wf2h, wf2l, buf0, buf1, buf2,
        (unsigned short*)buf2h, N);
    // s2 = da + 2*P(db)
    k_prop<NCLS, 0><<<bp, 256, 0, stream>>>(row_ptr, csrp, buf2h, buf1, nullptr, nullptr,
                                            buf3h, nullptr, N);
    // out = log_softmax(d0 - db + P(s2) + b2)
    k_prop<NCLS, 2><<<bp, 256, 0, stream>>>(row_ptr, csrp, buf3h, buf0, buf2, b2,
                                            nullptr, out, N);
}

// Round 9
// 357.185 us; speedup vs baseline: 1.4255x; 1.4255x over previous
//
#include <hip/hip_runtime.h>
#include <hip/hip_bf16.h>
#include <math.h>

// ---------------------------------------------------------------------------
// ChebNet (K=3) two-layer forward, restructured:
//   cheb(x,W) = x@W0 - x@W2 + P(x@W1 + 2*P(x@W2)) + b,  P = edge scatter-sum
// P applied in output feature space (64 then 40 dims).
// Edge scatter -> CSR-by-dst gather. CSR records are 4B (src only): gather
// tables are PRE-SCALED by dis[src] (folded into producer epilogues), and the
// remaining -dis[dst] factor is wave-uniform per node. k_count's atomicAdd
// return value doubles as the within-dst rank, so k_fill is atomic-free.
// GEMM1: fp32 A via bf16 hi/lo split (3 MFMA); GEMM2: bf16 A exact (2 MFMA).
// ---------------------------------------------------------------------------

#define FIN1 128
#define HID 64
#define NCLS 40

typedef __attribute__((ext_vector_type(8))) short sx8;
typedef __attribute__((ext_vector_type(4))) float fx4;

__device__ inline unsigned short f2bf(float f) {
    unsigned u = __float_as_uint(f);
    unsigned r = (u + 0x7FFF + ((u >> 16) & 1)) >> 16;  // RNE
    return (unsigned short)r;
}
__device__ inline float bf2f(unsigned short h) {
    return __uint_as_float((unsigned)h << 16);
}
__device__ inline unsigned pack2bf(float a, float b) {
    return (unsigned)f2bf(a) | ((unsigned)f2bf(b) << 16);
}
__device__ inline float lo2f(unsigned v) { return __uint_as_float(v << 16); }
__device__ inline float hi2f(unsigned v) { return __uint_as_float(v & 0xffff0000u); }

// count degrees; atomic return value = rank of edge within its dst
__global__ void k_count(const int* __restrict__ dst, int E, int* __restrict__ count,
                        int* __restrict__ rank) {
    int e = blockIdx.x * blockDim.x + threadIdx.x;
    if (e < E) rank[e] = atomicAdd(&count[dst[e]], 1);
}

// ---- hierarchical exclusive scan over count[N] ----
template <int EPT>
__global__ __launch_bounds__(256) void k_scan_part(const int* __restrict__ count, int N,
                                                   int* __restrict__ partial) {
    __shared__ int ws[4];
    int t = threadIdx.x;
    int lane = t & 63, w = t >> 6;
    int idx0 = blockIdx.x * 256 * EPT + t * EPT;
    int s = 0;
#pragma unroll
    for (int i = 0; i < EPT; ++i) {
        int idx = idx0 + i;
        if (idx < N) s += count[idx];
    }
#pragma unroll
    for (int d = 1; d < 64; d <<= 1) s += __shfl_xor(s, d);
    if (lane == 0) ws[w] = s;
    __syncthreads();
    if (t == 0) partial[blockIdx.x] = ws[0] + ws[1] + ws[2] + ws[3];
}

__global__ __launch_bounds__(256) void k_scan_mid(int* __restrict__ partial, int nb) {
    __shared__ int s[256];
    int t = threadIdx.x;
    int orig = (t < nb) ? partial[t] : 0;
    s[t] = orig;
    __syncthreads();
    for (int d = 1; d < 256; d <<= 1) {
        int v = (t >= d) ? s[t - d] : 0;
        __syncthreads();
        s[t] += v;
        __syncthreads();
    }
    if (t < nb) partial[t] = s[t] - orig;  // exclusive
}

template <int EPT>
__global__ __launch_bounds__(256) void k_scan_final(const int* __restrict__ count, int N,
                                                    const int* __restrict__ partial,
                                                    int* __restrict__ row_ptr,
                                                    float* __restrict__ dis) {
    __shared__ int wsum[4];
    int t = threadIdx.x;
    int lane = t & 63, w = t >> 6;
    int idx0 = blockIdx.x * 256 * EPT + t * EPT;
    int c[EPT];
    int s = 0;
#pragma unroll
    for (int i = 0; i < EPT; ++i) {
        int idx = idx0 + i;
        c[i] = (idx < N) ? count[idx] : 0;
        s += c[i];
    }
    int incl = s;
#pragma unroll
    for (int d = 1; d < 64; d <<= 1) {
        int u = __shfl_up(incl, d);
        if (lane >= d) incl += u;
    }
    if (lane == 63) wsum[w] = incl;
    __syncthreads();
    int woff = 0;
    for (int i = 0; i < w; ++i) woff += wsum[i];
    int off = partial[blockIdx.x] + woff + (incl - s);
#pragma unroll
    for (int i = 0; i < EPT; ++i) {
        int idx = idx0 + i;
        if (idx < N) {
            row_ptr[idx] = off;
            dis[idx] = (c[i] > 0) ? rsqrtf((float)c[i]) : 0.0f;
            off += c[i];
            if (idx == N - 1) row_ptr[N] = off;
        }
    }
}

// atomic-free fill: pos = row_ptr[dst] + rank
__global__ void k_fill(const int* __restrict__ src, const int* __restrict__ dst, int E,
                       const int* __restrict__ rank, const int* __restrict__ row_ptr,
                       unsigned* __restrict__ csr_src) {
    int e = blockIdx.x * blockDim.x + threadIdx.x;
    if (e < E) {
        int d = dst[e];
        csr_src[row_ptr[d] + rank[e]] = (unsigned)src[e];
    }
}

// Pre-swizzle W[3][FIN][FOE] (fp32) into MFMA B-fragment layout, hi/lo bf16.
template <int NS, int T, int FIN, int FOE>
__global__ void k_wprep(const float* __restrict__ W, unsigned short* __restrict__ hi,
                        unsigned short* __restrict__ lo) {
    int idx = blockIdx.x * 256 + threadIdx.x;
    constexpr int total = NS * T * 64 * 8;
    if (idx >= total) return;
    int i = idx & 7;
    int l = (idx >> 3) & 63;
    int t = (idx >> 9) % T;
    int s = idx / (512 * T);
    int k = s * 32 + (l >> 4) * 8 + i;
    int col = t * 16 + (l & 15);
    float w = 0.0f;
    if (col < 3 * FOE) {
        int m = col / FOE;
        int c = col - m * FOE;
        w = W[((size_t)m * FIN + k) * FOE + c];
    }
    unsigned short h = f2bf(w);
    hi[idx] = h;
    lo[idx] = f2bf(w - bf2f(h));
}

// MFMA GEMM layer-1, fp32 A (hi/lo split, 3 MFMA): C{0,1,2} = A@W[m] (fp32);
// C2 additionally as bf16 table PRE-SCALED by dis[r] (ushort stride 64).
template <int FIN, int T, int NS, int FOE>
__global__ __launch_bounds__(256, 3) void k_gemm_mfma(
    const float* __restrict__ A, const unsigned short* __restrict__ Whi,
    const unsigned short* __restrict__ Wlo, const float* __restrict__ dis,
    float* __restrict__ C0, float* __restrict__ C1, float* __restrict__ C2,
    unsigned short* __restrict__ Th, int N) {
    int tid = threadIdx.x;
    int w = tid >> 6, l = tid & 63;
    int row0 = blockIdx.x * 128 + w * 32;
    int rl = l & 15, kg = l >> 4;

    fx4 acc[2][T];
#pragma unroll
    for (int rt = 0; rt < 2; ++rt)
#pragma unroll
        for (int t = 0; t < T; ++t) acc[rt][t] = (fx4)0.0f;

    for (int s = 0; s < NS; ++s) {
        int k0 = s * 32 + kg * 8;
        sx8 ahi[2], alo[2];
#pragma unroll
        for (int rt = 0; rt < 2; ++rt) {
            int r = min(row0 + rt * 16 + rl, N - 1);
            const fx4* ap = (const fx4*)(A + (size_t)r * FIN + k0);
            fx4 a0 = ap[0];
            fx4 a1 = ap[1];
#pragma unroll
            for (int j = 0; j < 4; ++j) {
                unsigned short h0 = f2bf(a0[j]);
                unsigned short h1 = f2bf(a1[j]);
                ahi[rt][j] = (short)h0;
                ahi[rt][j + 4] = (short)h1;
                alo[rt][j] = (short)f2bf(a0[j] - bf2f(h0));
                alo[rt][j + 4] = (short)f2bf(a1[j] - bf2f(h1));
            }
        }
        const sx8* wh = (const sx8*)(Whi + ((size_t)(s * T) * 64 + l) * 8);
        const sx8* wl = (const sx8*)(Wlo + ((size_t)(s * T) * 64 + l) * 8);
#pragma unroll
        for (int t = 0; t < T; ++t) {
            sx8 bh = wh[t * 64];
            sx8 bl = wl[t * 64];
#pragma unroll
            for (int rt = 0; rt < 2; ++rt) {
                acc[rt][t] = __builtin_amdgcn_mfma_f32_16x16x32_bf16(ahi[rt], bh, acc[rt][t], 0, 0, 0);
                acc[rt][t] = __builtin_amdgcn_mfma_f32_16x16x32_bf16(ahi[rt], bl, acc[rt][t], 0, 0, 0);
                acc[rt][t] = __builtin_amdgcn_mfma_f32_16x16x32_bf16(alo[rt], bh, acc[rt][t], 0, 0, 0);
            }
        }
    }

    float ds_[2][4];
#pragma unroll
    for (int rt = 0; rt < 2; ++rt)
#pragma unroll
        for (int j = 0; j < 4; ++j)
            ds_[rt][j] = dis[min(row0 + rt * 16 + kg * 4 + j, N - 1)];

#pragma unroll
    for (int rt = 0; rt < 2; ++rt)
#pragma unroll
        for (int t = 0; t < T; ++t) {
            int col = t * 16 + rl;
            int m = col / FOE;
            int cc = col - m * FOE;
            if (m < 3) {
                float* Cm = (m == 0) ? C0 : ((m == 1) ? C1 : C2);
#pragma unroll
                for (int j = 0; j < 4; ++j) {
                    int r = row0 + rt * 16 + kg * 4 + j;
                    if (r < N) {
                        Cm[(size_t)r * FOE + cc] = acc[rt][t][j];
                        if (m == 2)
                            Th[(size_t)r * 64 + cc] = f2bf(ds_[rt][j] * acc[rt][t][j]);
                    }
                }
            }
        }
}

// MFMA GEMM layer-2, bf16 A (exact, 2 MFMA): C{0,1,2} = A@W[m] (fp32);
// C2 additionally as bf16 table PRE-SCALED by dis[r] (ushort stride 64).
template <int FIN, int T, int NS, int FOE>
__global__ __launch_bounds__(256, 3) void k_gemm_mfma_bf(
    const unsigned short* __restrict__ A, const unsigned short* __restrict__ Whi,
    const unsigned short* __restrict__ Wlo, const float* __restrict__ dis,
    float* __restrict__ C0, float* __restrict__ C1, float* __restrict__ C2,
    unsigned short* __restrict__ Th, int N) {
    int tid = threadIdx.x;
    int w = tid >> 6, l = tid & 63;
    int row0 = blockIdx.x * 128 + w * 32;
    int rl = l & 15, kg = l >> 4;

    fx4 acc[2][T];
#pragma unroll
    for (int rt = 0; rt < 2; ++rt)
#pragma unroll
        for (int t = 0; t < T; ++t) acc[rt][t] = (fx4)0.0f;

    for (int s = 0; s < NS; ++s) {
        int k0 = s * 32 + kg * 8;
        sx8 a[2];
#pragma unroll
        for (int rt = 0; rt < 2; ++rt) {
            int r = min(row0 + rt * 16 + rl, N - 1);
            a[rt] = *(const sx8*)(A + (size_t)r * FIN + k0);
        }
        const sx8* wh = (const sx8*)(Whi + ((size_t)(s * T) * 64 + l) * 8);
        const sx8* wl = (const sx8*)(Wlo + ((size_t)(s * T) * 64 + l) * 8);
#pragma unroll
        for (int t = 0; t < T; ++t) {
            sx8 bh = wh[t * 64];
            sx8 bl = wl[t * 64];
#pragma unroll
            for (int rt = 0; rt < 2; ++rt) {
                acc[rt][t] = __builtin_amdgcn_mfma_f32_16x16x32_bf16(a[rt], bh, acc[rt][t], 0, 0, 0);
                acc[rt][t] = __builtin_amdgcn_mfma_f32_16x16x32_bf16(a[rt], bl, acc[rt][t], 0, 0, 0);
            }
        }
    }

    float ds_[2][4];
#pragma unroll
    for (int rt = 0; rt < 2; ++rt)
#pragma unroll
        for (int j = 0; j < 4; ++j)
            ds_[rt][j] = dis[min(row0 + rt * 16 + kg * 4 + j, N - 1)];

#pragma unroll
    for (int rt = 0; rt < 2; ++rt)
#pragma unroll
        for (int t = 0; t < T; ++t) {
            int col = t * 16 + rl;
            int m = col / FOE;
            int cc = col - m * FOE;
            if (m < 3) {
                float* Cm = (m == 0) ? C0 : ((m == 1) ? C1 : C2);
#pragma unroll
                for (int j = 0; j < 4; ++j) {
                    int r = row0 + rt * 16 + kg * 4 + j;
                    if (r < N) {
                        Cm[(size_t)r * FOE + cc] = acc[rt][t][j];
                        if (m == 2)
                            Th[(size_t)r * 64 + cc] = f2bf(ds_[rt][j] * acc[rt][t][j]);
                    }
                }
            }
        }
}

// CSR gather-prop, dual-edge form, pre-scaled tables. One wave per dst node.
// Table rows: 32 dwords (64 bf16 feats), pre-scaled by dis[src]. Per-node
// factor -dis[wid] applied once in epilogue. 32-edge metadata chunks (one
// dword per lane), 16 gathers in flight per lane (2 edges/instruction).
// MODE 0: outh = packbf16(dis[wid]*(o0 - 2*dis[wid]*acc))    [table for next P]
// MODE 1: outh = packbf16(relu(o0 - o1 - dis[wid]*acc + bias))  [unscaled]
// MODE 2: outf = log_softmax(o0 - o1 - dis[wid]*acc + bias) over F (fp32)
template <int F, int MODE>
__global__ void k_prop(const int* __restrict__ row_ptr,
                       const unsigned* __restrict__ csr_src,
                       const unsigned* __restrict__ tab,
                       const float* __restrict__ dis,
                       const float* __restrict__ o0, const float* __restrict__ o1,
                       const float* __restrict__ bias,
                       unsigned* __restrict__ outh, float* __restrict__ outf, int N) {
    constexpr int FH = F / 2;
    int wid = (blockIdx.x * blockDim.x + threadIdx.x) >> 6;
    int lane = threadIdx.x & 63;
    if (wid >= N) return;
    int g = lane >> 5;   // edge slot within a pair
    int c = lane & 31;   // feature-pair index
    int beg = row_ptr[wid];
    int end = row_ptr[wid + 1];
    float wd = dis[wid];
    float ax = 0.0f, ay = 0.0f;
    for (int j = beg; j < end; j += 32) {
        unsigned md = csr_src[j + (lane & 31)];  // 32-edge chunk, coalesced
#pragma unroll
        for (int t = 0; t < 16; ++t) {
            int idx = 2 * t + g;
            int s = __shfl((int)md, idx);
            unsigned v = tab[(size_t)s * 32 + c];
            v = (j + idx < end) ? v : 0u;
            ax += lo2f(v);
            ay += hi2f(v);
        }
    }
    ax += __shfl_xor(ax, 32);
    ay += __shfl_xor(ay, 32);

    if (MODE == 0) {
        if (g == 0 && c < FH) {
            float2 o = ((const float2*)o0)[(size_t)wid * FH + c];
            float s0 = o.x - 2.0f * wd * ax;
            float s1 = o.y - 2.0f * wd * ay;
            outh[(size_t)wid * 32 + c] = pack2bf(wd * s0, wd * s1);
        }
    } else if (MODE == 1) {
        if (g == 0 && c < FH) {
            float2 o = ((const float2*)o0)[(size_t)wid * FH + c];
            float2 q = ((const float2*)o1)[(size_t)wid * FH + c];
            float2 b = ((const float2*)bias)[c];
            float z0 = fmaxf(o.x - q.x - wd * ax + b.x, 0.0f);
            float z1 = fmaxf(o.y - q.y - wd * ay + b.y, 0.0f);
            outh[(size_t)wid * 32 + c] = pack2bf(z0, z1);
        }
    } else {
        float z0 = -INFINITY, z1 = -INFINITY;
        if (g == 0 && c < FH) {
            float2 o = ((const float2*)o0)[(size_t)wid * FH + c];
            float2 q = ((const float2*)o1)[(size_t)wid * FH + c];
            float2 b = ((const float2*)bias)[c];
            z0 = o.x - q.x - wd * ax + b.x;
            z1 = o.y - q.y - wd * ay + b.y;
        }
        float m = fmaxf(z0, z1);
#pragma unroll
        for (int d = 32; d; d >>= 1) m = fmaxf(m, __shfl_xor(m, d));
        float e0 = (g == 0 && c < FH) ? expf(z0 - m) : 0.0f;
        float e1 = (g == 0 && c < FH) ? expf(z1 - m) : 0.0f;
        float l = e0 + e1;
#pragma unroll
        for (int d = 32; d; d >>= 1) l += __shfl_xor(l, d);
        if (g == 0 && c < FH) {
            float lg = m + logf(l);
            ((float2*)outf)[(size_t)wid * FH + c] = make_float2(z0 - lg, z1 - lg);
        }
    }
}

extern "C" void kernel_launch(void* const* d_in, const int* in_sizes, int n_in,
                              void* d_out, int out_size, void* d_ws, size_t ws_size,
                              hipStream_t stream) {
    const float* x = (const float*)d_in[0];
    const int* ei = (const int*)d_in[1];
    const float* W1 = (const float*)d_in[2];
    const float* b1 = (const float*)d_in[3];
    const float* W2 = (const float*)d_in[4];
    const float* b2 = (const float*)d_in[5];
    float* out = (float*)d_out;

    const int N = in_sizes[0] / FIN1;  // 100000
    const int E = in_sizes[1] / 2;     // 1600000
    const int* src = ei;
    const int* dst = ei + E;

    // workspace carve (256B aligned)
    char* p = (char*)d_ws;
    auto alloc = [&](size_t bytes) -> void* {
        void* r = (void*)p;
        p += (bytes + 255) & ~(size_t)255;
        return r;
    };
    int* count = (int*)alloc((size_t)N * 4);
    int* row_ptr = (int*)alloc((size_t)(N + 1) * 4);
    float* dis = (float*)alloc((size_t)N * 4);
    int* partial = (int*)alloc(256 * 4);
    int* rank = (int*)alloc((size_t)E * 4);
    unsigned* csr_src = (unsigned*)alloc(((size_t)E + 32) * 4);  // 4B records + pad
    float* buf0 = (float*)alloc((size_t)N * HID * 4);  // c0 / d0 (fp32)
    float* buf1 = (float*)alloc((size_t)N * HID * 4);  // ca / da (fp32)
    float* buf2 = (float*)alloc((size_t)N * HID * 4);  // cb / db (fp32)
    unsigned* blkA = (unsigned*)alloc((size_t)N * 32 * 4);  // cb/db table (scaled)
    unsigned* blkB = (unsigned*)alloc((size_t)N * 32 * 4);  // s/s2 table (scaled)
    unsigned* buf4h = (unsigned*)alloc((size_t)N * 32 * 4); // h bf16 (unscaled)
    // W fragment buffers (hi/lo bf16, B-frag layout)
    constexpr int W1FRAG = 4 * 12 * 64 * 8;  // 24576
    constexpr int W2FRAG = 2 * 8 * 64 * 8;   // 8192
    unsigned short* wf1h = (unsigned short*)alloc((size_t)W1FRAG * 2);
    unsigned short* wf1l = (unsigned short*)alloc((size_t)W1FRAG * 2);
    unsigned short* wf2h = (unsigned short*)alloc((size_t)W2FRAG * 2);
    unsigned short* wf2l = (unsigned short*)alloc((size_t)W2FRAG * 2);

    const int be = (E + 255) / 256;
    const int bg = (N + 127) / 128;       // MFMA gemm blocks (BM=128)
    const int bp = (N * 64 + 255) / 256;  // one wave per node
    constexpr int EPB = 256 * 8;
    const int nb = (N + EPB - 1) / EPB;   // 49 blocks for N=100000

    // ---- W fragment prep (independent of graph) ----
    k_wprep<4, 12, FIN1, HID><<<(W1FRAG + 255) / 256, 256, 0, stream>>>(W1, wf1h, wf1l);
    k_wprep<2, 8, HID, NCLS><<<(W2FRAG + 255) / 256, 256, 0, stream>>>(W2, wf2h, wf2l);

    // ---- graph structure: degree(+rank), row_ptr, fill ----
    hipMemsetAsync(count, 0, (size_t)N * 4, stream);
    hipMemsetAsync(csr_src + E, 0, (size_t)32 * 4, stream);  // zero pad records
    k_count<<<be, 256, 0, stream>>>(dst, E, count, rank);
    k_scan_part<8><<<nb, 256, 0, stream>>>(count, N, partial);
    k_scan_mid<<<1, 256, 0, stream>>>(partial, nb);
    k_scan_final<8><<<nb, 256, 0, stream>>>(count, N, partial, row_ptr, dis);
    k_fill<<<be, 256, 0, stream>>>(src, dst, E, rank, row_ptr, csr_src);

    // ---- layer 1: x[N,128] -> h[N,64] ----
    k_gemm_mfma<FIN1, 12, 4, HID><<<bg, 256, 0, stream>>>(
        x, wf1h, wf1l, dis, buf0, buf1, buf2, (unsigned short*)blkA, N);
    // s = ca + 2*P(cb): table out pre-scaled by dis[wid]
    k_prop<HID, 0><<<bp, 256, 0, stream>>>(row_ptr, csr_src, blkA, dis, buf1, nullptr,
                                           nullptr, blkB, nullptr, N);
    // h = relu(c0 - cb + P(s) + b1): unscaled bf16 for GEMM2
    k_prop<HID, 1><<<bp, 256, 0, stream>>>(row_ptr, csr_src, blkB, dis, buf0, buf2,
                                           b1, buf4h, nullptr, N);

    // ---- layer 2: h[N,64] -> out[N,40] ----
    k_gemm_mfma_bf<HID, 8, 2, NCLS><<<bg, 256, 0, stream>>>(
        (const unsigned short*)buf4h, wf2h, wf2l, dis, buf0, buf1, buf2,
        (unsigned short*)blkA, N);
    // s2 = da + 2*P(db)
    k_prop<NCLS, 0><<<bp, 256, 0, stream>>>(row_ptr, csr_src, blkA, dis, buf1, nullptr,
                                            nullptr, blkB, nullptr, N);
    // out = log_softmax(d0 - db + P(s2) + b2)
    k_prop<NCLS, 2><<<bp, 256, 0, stream>>>(row_ptr, csr_src, blkB, dis, buf0, buf2,
                                            b2, nullptr, out, N);
}

// Round 10
// 351.860 us; speedup vs baseline: 1.4471x; 1.0151x over previous
//
#include <hip/hip_runtime.h>
#include <hip/hip_bf16.h>
#include <math.h>

// ---------------------------------------------------------------------------
// ChebNet (K=3) two-layer forward, restructured:
//   cheb(x,W) = x@(W0-W2) + P(x@W1 + 2*P(x@W2)) + b,  P = edge scatter-sum
// (W0-W2 folded at wprep). P applied in output feature space (64/40 dims).
// Edge scatter -> CSR-by-dst gather; 4B records (src only): gather tables
// pre-scaled by dis[src]; -dis[dst] factor is wave-uniform per node.
// k_count's atomicAdd return = within-dst rank -> k_fill is atomic-free.
// All GEMM1 outputs bf16 (dd, ca, cb-table); GEMM2: dd2 fp32 (softmax input),
// da bf16, db-table bf16. GEMM: 16 rows/wave (high occupancy), no LDS.
// ---------------------------------------------------------------------------

#define FIN1 128
#define HID 64
#define NCLS 40

typedef __attribute__((ext_vector_type(8))) short sx8;
typedef __attribute__((ext_vector_type(4))) float fx4;

__device__ inline unsigned short f2bf(float f) {
    unsigned u = __float_as_uint(f);
    unsigned r = (u + 0x7FFF + ((u >> 16) & 1)) >> 16;  // RNE
    return (unsigned short)r;
}
__device__ inline float bf2f(unsigned short h) {
    return __uint_as_float((unsigned)h << 16);
}
__device__ inline unsigned pack2bf(float a, float b) {
    return (unsigned)f2bf(a) | ((unsigned)f2bf(b) << 16);
}
__device__ inline float lo2f(unsigned v) { return __uint_as_float(v << 16); }
__device__ inline float hi2f(unsigned v) { return __uint_as_float(v & 0xffff0000u); }

// count degrees; atomic return value = rank of edge within its dst
__global__ void k_count(const int* __restrict__ dst, int E, int* __restrict__ count,
                        int* __restrict__ rank) {
    int e = blockIdx.x * blockDim.x + threadIdx.x;
    if (e < E) rank[e] = atomicAdd(&count[dst[e]], 1);
}

// ---- hierarchical exclusive scan over count[N] ----
template <int EPT>
__global__ __launch_bounds__(256) void k_scan_part(const int* __restrict__ count, int N,
                                                   int* __restrict__ partial) {
    __shared__ int ws[4];
    int t = threadIdx.x;
    int lane = t & 63, w = t >> 6;
    int idx0 = blockIdx.x * 256 * EPT + t * EPT;
    int s = 0;
#pragma unroll
    for (int i = 0; i < EPT; ++i) {
        int idx = idx0 + i;
        if (idx < N) s += count[idx];
    }
#pragma unroll
    for (int d = 1; d < 64; d <<= 1) s += __shfl_xor(s, d);
    if (lane == 0) ws[w] = s;
    __syncthreads();
    if (t == 0) partial[blockIdx.x] = ws[0] + ws[1] + ws[2] + ws[3];
}

__global__ __launch_bounds__(256) void k_scan_mid(int* __restrict__ partial, int nb) {
    __shared__ int s[256];
    int t = threadIdx.x;
    int orig = (t < nb) ? partial[t] : 0;
    s[t] = orig;
    __syncthreads();
    for (int d = 1; d < 256; d <<= 1) {
        int v = (t >= d) ? s[t - d] : 0;
        __syncthreads();
        s[t] += v;
        __syncthreads();
    }
    if (t < nb) partial[t] = s[t] - orig;  // exclusive
}

template <int EPT>
__global__ __launch_bounds__(256) void k_scan_final(const int* __restrict__ count, int N,
                                                    const int* __restrict__ partial,
                                                    int* __restrict__ row_ptr,
                                                    float* __restrict__ dis) {
    __shared__ int wsum[4];
    int t = threadIdx.x;
    int lane = t & 63, w = t >> 6;
    int idx0 = blockIdx.x * 256 * EPT + t * EPT;
    int c[EPT];
    int s = 0;
#pragma unroll
    for (int i = 0; i < EPT; ++i) {
        int idx = idx0 + i;
        c[i] = (idx < N) ? count[idx] : 0;
        s += c[i];
    }
    int incl = s;
#pragma unroll
    for (int d = 1; d < 64; d <<= 1) {
        int u = __shfl_up(incl, d);
        if (lane >= d) incl += u;
    }
    if (lane == 63) wsum[w] = incl;
    __syncthreads();
    int woff = 0;
    for (int i = 0; i < w; ++i) woff += wsum[i];
    int off = partial[blockIdx.x] + woff + (incl - s);
#pragma unroll
    for (int i = 0; i < EPT; ++i) {
        int idx = idx0 + i;
        if (idx < N) {
            row_ptr[idx] = off;
            dis[idx] = (c[i] > 0) ? rsqrtf((float)c[i]) : 0.0f;
            off += c[i];
            if (idx == N - 1) row_ptr[N] = off;
        }
    }
}

// atomic-free fill: pos = row_ptr[dst] + rank
__global__ void k_fill(const int* __restrict__ src, const int* __restrict__ dst, int E,
                       const int* __restrict__ rank, const int* __restrict__ row_ptr,
                       unsigned* __restrict__ csr_src) {
    int e = blockIdx.x * blockDim.x + threadIdx.x;
    if (e < E) {
        int d = dst[e];
        csr_src[row_ptr[d] + rank[e]] = (unsigned)src[e];
    }
}

// Pre-swizzle into MFMA B-fragment layout, hi/lo bf16, with W0-W2 folding:
// logical matrix m: 0 -> W[0]-W[2], 1 -> W[1], 2 -> W[2].
template <int NS, int T, int FIN, int FOE>
__global__ void k_wprep(const float* __restrict__ W, unsigned short* __restrict__ hi,
                        unsigned short* __restrict__ lo) {
    int idx = blockIdx.x * 256 + threadIdx.x;
    constexpr int total = NS * T * 64 * 8;
    if (idx >= total) return;
    int i = idx & 7;
    int l = (idx >> 3) & 63;
    int t = (idx >> 9) % T;
    int s = idx / (512 * T);
    int k = s * 32 + (l >> 4) * 8 + i;
    int col = t * 16 + (l & 15);
    float w = 0.0f;
    if (col < 3 * FOE) {
        int m = col / FOE;
        int c = col - m * FOE;
        if (m == 0)
            w = W[((size_t)0 * FIN + k) * FOE + c] - W[((size_t)2 * FIN + k) * FOE + c];
        else
            w = W[((size_t)m * FIN + k) * FOE + c];
    }
    unsigned short h = f2bf(w);
    hi[idx] = h;
    lo[idx] = f2bf(w - bf2f(h));
}

// MFMA GEMM layer-1, fp32 A (hi/lo split, 3 MFMA), 16 rows/wave.
// Outputs (all bf16, ushort stride 64): OHd = x@(W0-W2), OHa = x@W1,
// Th = dis[r] * (x@W2)  [gather table].
template <int FIN, int T, int NS, int FOE>
__global__ __launch_bounds__(256, 6) void k_gemm_mfma(
    const float* __restrict__ A, const unsigned short* __restrict__ Whi,
    const unsigned short* __restrict__ Wlo, const float* __restrict__ dis,
    unsigned short* __restrict__ OHd, unsigned short* __restrict__ OHa,
    unsigned short* __restrict__ Th, int N) {
    int tid = threadIdx.x;
    int w = tid >> 6, l = tid & 63;
    int row0 = blockIdx.x * 64 + w * 16;
    int rl = l & 15, kg = l >> 4;

    fx4 acc[T];
#pragma unroll
    for (int t = 0; t < T; ++t) acc[t] = (fx4)0.0f;

    for (int s = 0; s < NS; ++s) {
        int k0 = s * 32 + kg * 8;
        int r = min(row0 + rl, N - 1);
        const fx4* ap = (const fx4*)(A + (size_t)r * FIN + k0);
        fx4 a0 = ap[0];
        fx4 a1 = ap[1];
        sx8 ahi, alo;
#pragma unroll
        for (int j = 0; j < 4; ++j) {
            unsigned short h0 = f2bf(a0[j]);
            unsigned short h1 = f2bf(a1[j]);
            ahi[j] = (short)h0;
            ahi[j + 4] = (short)h1;
            alo[j] = (short)f2bf(a0[j] - bf2f(h0));
            alo[j + 4] = (short)f2bf(a1[j] - bf2f(h1));
        }
        const sx8* wh = (const sx8*)(Whi + ((size_t)(s * T) * 64 + l) * 8);
        const sx8* wl = (const sx8*)(Wlo + ((size_t)(s * T) * 64 + l) * 8);
#pragma unroll
        for (int t = 0; t < T; ++t) {
            sx8 bh = wh[t * 64];
            sx8 bl = wl[t * 64];
            acc[t] = __builtin_amdgcn_mfma_f32_16x16x32_bf16(ahi, bh, acc[t], 0, 0, 0);
            acc[t] = __builtin_amdgcn_mfma_f32_16x16x32_bf16(ahi, bl, acc[t], 0, 0, 0);
            acc[t] = __builtin_amdgcn_mfma_f32_16x16x32_bf16(alo, bh, acc[t], 0, 0, 0);
        }
    }

    float ds_[4];
#pragma unroll
    for (int j = 0; j < 4; ++j) ds_[j] = dis[min(row0 + kg * 4 + j, N - 1)];

#pragma unroll
    for (int t = 0; t < T; ++t) {
        int col = t * 16 + rl;
        int m = col / FOE;
        int cc = col - m * FOE;
        if (m < 3) {
#pragma unroll
            for (int j = 0; j < 4; ++j) {
                int r = row0 + kg * 4 + j;
                if (r < N) {
                    if (m == 0) OHd[(size_t)r * 64 + cc] = f2bf(acc[t][j]);
                    else if (m == 1) OHa[(size_t)r * 64 + cc] = f2bf(acc[t][j]);
                    else Th[(size_t)r * 64 + cc] = f2bf(ds_[j] * acc[t][j]);
                }
            }
        }
    }
}

// MFMA GEMM layer-2, bf16 A (exact, 2 MFMA), 16 rows/wave.
// Outputs: C0 = h@(W0-W2) fp32 (stride FOE, softmax input), OHa = h@W1 bf16,
// Th = dis[r] * (h@W2) bf16 table (ushort stride 64).
template <int FIN, int T, int NS, int FOE>
__global__ __launch_bounds__(256, 6) void k_gemm_mfma_bf(
    const unsigned short* __restrict__ A, const unsigned short* __restrict__ Whi,
    const unsigned short* __restrict__ Wlo, const float* __restrict__ dis,
    float* __restrict__ C0, unsigned short* __restrict__ OHa,
    unsigned short* __restrict__ Th, int N) {
    int tid = threadIdx.x;
    int w = tid >> 6, l = tid & 63;
    int row0 = blockIdx.x * 64 + w * 16;
    int rl = l & 15, kg = l >> 4;

    fx4 acc[T];
#pragma unroll
    for (int t = 0; t < T; ++t) acc[t] = (fx4)0.0f;

    for (int s = 0; s < NS; ++s) {
        int k0 = s * 32 + kg * 8;
        int r = min(row0 + rl, N - 1);
        sx8 a = *(const sx8*)(A + (size_t)r * FIN + k0);
        const sx8* wh = (const sx8*)(Whi + ((size_t)(s * T) * 64 + l) * 8);
        const sx8* wl = (const sx8*)(Wlo + ((size_t)(s * T) * 64 + l) * 8);
#pragma unroll
        for (int t = 0; t < T; ++t) {
            sx8 bh = wh[t * 64];
            sx8 bl = wl[t * 64];
            acc[t] = __builtin_amdgcn_mfma_f32_16x16x32_bf16(a, bh, acc[t], 0, 0, 0);
            acc[t] = __builtin_amdgcn_mfma_f32_16x16x32_bf16(a, bl, acc[t], 0, 0, 0);
        }
    }

    float ds_[4];
#pragma unroll
    for (int j = 0; j < 4; ++j) ds_[j] = dis[min(row0 + kg * 4 + j, N - 1)];

#pragma unroll
    for (int t = 0; t < T; ++t) {
        int col = t * 16 + rl;
        int m = col / FOE;
        int cc = col - m * FOE;
        if (m < 3) {
#pragma unroll
            for (int j = 0; j < 4; ++j) {
                int r = row0 + kg * 4 + j;
                if (r < N) {
                    if (m == 0) C0[(size_t)r * FOE + cc] = acc[t][j];
                    else if (m == 1) OHa[(size_t)r * 64 + cc] = f2bf(acc[t][j]);
                    else Th[(size_t)r * 64 + cc] = f2bf(ds_[j] * acc[t][j]);
                }
            }
        }
    }
}

// CSR gather-prop, dual-edge form, pre-scaled tables. One wave per dst node.
// Table rows: 32 dwords (64 bf16 feats), pre-scaled by dis[src]. Per-node
// factor -dis[wid] applied once in epilogue. 32-edge metadata chunks.
// MODE 0: outh = packbf16(dis[wid]*(oh - 2*dis[wid]*acc))   [table for next P]
// MODE 1: outh = packbf16(relu(oh - dis[wid]*acc + bias))   [oh = dd bf16]
// MODE 2: outf = log_softmax(o0f - dis[wid]*acc + bias) over F (o0f fp32)
template <int F, int MODE>
__global__ void k_prop(const int* __restrict__ row_ptr,
                       const unsigned* __restrict__ csr_src,
                       const unsigned* __restrict__ tab,
                       const float* __restrict__ dis,
                       const unsigned* __restrict__ oh,
                       const float* __restrict__ o0f,
                       const float* __restrict__ bias,
                       unsigned* __restrict__ outh, float* __restrict__ outf, int N) {
    constexpr int FH = F / 2;
    int wid = (blockIdx.x * blockDim.x + threadIdx.x) >> 6;
    int lane = threadIdx.x & 63;
    if (wid >= N) return;
    int g = lane >> 5;   // edge slot within a pair
    int c = lane & 31;   // feature-pair index
    int beg = row_ptr[wid];
    int end = row_ptr[wid + 1];
    float wd = dis[wid];
    float ax = 0.0f, ay = 0.0f;
    for (int j = beg; j < end; j += 32) {
        unsigned md = csr_src[j + (lane & 31)];  // 32-edge chunk, coalesced
#pragma unroll
        for (int t = 0; t < 16; ++t) {
            int idx = 2 * t + g;
            int s = __shfl((int)md, idx);
            unsigned v = tab[(size_t)s * 32 + c];
            v = (j + idx < end) ? v : 0u;
            ax += lo2f(v);
            ay += hi2f(v);
        }
    }
    ax += __shfl_xor(ax, 32);
    ay += __shfl_xor(ay, 32);

    if (MODE == 0) {
        if (g == 0 && c < FH) {
            unsigned ov = oh[(size_t)wid * 32 + c];
            float s0 = lo2f(ov) - 2.0f * wd * ax;
            float s1 = hi2f(ov) - 2.0f * wd * ay;
            outh[(size_t)wid * 32 + c] = pack2bf(wd * s0, wd * s1);
        }
    } else if (MODE == 1) {
        if (g == 0 && c < FH) {
            unsigned ov = oh[(size_t)wid * 32 + c];
            float2 b = ((const float2*)bias)[c];
            float z0 = fmaxf(lo2f(ov) - wd * ax + b.x, 0.0f);
            float z1 = fmaxf(hi2f(ov) - wd * ay + b.y, 0.0f);
            outh[(size_t)wid * 32 + c] = pack2bf(z0, z1);
        }
    } else {
        float z0 = -INFINITY, z1 = -INFINITY;
        if (g == 0 && c < FH) {
            float2 o = ((const float2*)o0f)[(size_t)wid * FH + c];
            float2 b = ((const float2*)bias)[c];
            z0 = o.x - wd * ax + b.x;
            z1 = o.y - wd * ay + b.y;
        }
        float m = fmaxf(z0, z1);
#pragma unroll
        for (int d = 32; d; d >>= 1) m = fmaxf(m, __shfl_xor(m, d));
        float e0 = (g == 0 && c < FH) ? expf(z0 - m) : 0.0f;
        float e1 = (g == 0 && c < FH) ? expf(z1 - m) : 0.0f;
        float l = e0 + e1;
#pragma unroll
        for (int d = 32; d; d >>= 1) l += __shfl_xor(l, d);
        if (g == 0 && c < FH) {
            float lg = m + logf(l);
            ((float2*)outf)[(size_t)wid * FH + c] = make_float2(z0 - lg, z1 - lg);
        }
    }
}

extern "C" void kernel_launch(void* const* d_in, const int* in_sizes, int n_in,
                              void* d_out, int out_size, void* d_ws, size_t ws_size,
                              hipStream_t stream) {
    const float* x = (const float*)d_in[0];
    const int* ei = (const int*)d_in[1];
    const float* W1 = (const float*)d_in[2];
    const float* b1 = (const float*)d_in[3];
    const float* W2 = (const float*)d_in[4];
    const float* b2 = (const float*)d_in[5];
    float* out = (float*)d_out;

    const int N = in_sizes[0] / FIN1;  // 100000
    const int E = in_sizes[1] / 2;     // 1600000
    const int* src = ei;
    const int* dst = ei + E;

    // workspace carve (256B aligned)
    char* p = (char*)d_ws;
    auto alloc = [&](size_t bytes) -> void* {
        void* r = (void*)p;
        p += (bytes + 255) & ~(size_t)255;
        return r;
    };
    int* count = (int*)alloc((size_t)N * 4);
    int* row_ptr = (int*)alloc((size_t)(N + 1) * 4);
    float* dis = (float*)alloc((size_t)N * 4);
    int* partial = (int*)alloc(256 * 4);
    int* rank = (int*)alloc((size_t)E * 4);
    unsigned* csr_src = (unsigned*)alloc(((size_t)E + 32) * 4);  // 4B records + pad
    float* buf0 = (float*)alloc((size_t)N * NCLS * 4);      // dd2 fp32 (softmax in)
    unsigned* blkA = (unsigned*)alloc((size_t)N * 32 * 4);  // cb/db table (scaled)
    unsigned* blkB = (unsigned*)alloc((size_t)N * 32 * 4);  // s/s2 table (scaled)
    unsigned* bufDD = (unsigned*)alloc((size_t)N * 32 * 4); // dd1 bf16; then da
    unsigned* bufCA = (unsigned*)alloc((size_t)N * 32 * 4); // ca bf16
    unsigned* buf4h = (unsigned*)alloc((size_t)N * 32 * 4); // h bf16
    // W fragment buffers (hi/lo bf16, B-frag layout)
    constexpr int W1FRAG = 4 * 12 * 64 * 8;  // 24576
    constexpr int W2FRAG = 2 * 8 * 64 * 8;   // 8192
    unsigned short* wf1h = (unsigned short*)alloc((size_t)W1FRAG * 2);
    unsigned short* wf1l = (unsigned short*)alloc((size_t)W1FRAG * 2);
    unsigned short* wf2h = (unsigned short*)alloc((size_t)W2FRAG * 2);
    unsigned short* wf2l = (unsigned short*)alloc((size_t)W2FRAG * 2);

    const int be = (E + 255) / 256;
    const int bg = (N + 63) / 64;         // MFMA gemm blocks (64 rows/block)
    const int bp = (N * 64 + 255) / 256;  // one wave per node
    constexpr int EPB = 256 * 8;
    const int nb = (N + EPB - 1) / EPB;   // 49 blocks for N=100000

    // ---- W fragment prep (independent of graph) ----
    k_wprep<4, 12, FIN1, HID><<<(W1FRAG + 255) / 256, 256, 0, stream>>>(W1, wf1h, wf1l);
    k_wprep<2, 8, HID, NCLS><<<(W2FRAG + 255) / 256, 256, 0, stream>>>(W2, wf2h, wf2l);

    // ---- graph structure: degree(+rank), row_ptr, fill ----
    hipMemsetAsync(count, 0, (size_t)N * 4, stream);
    hipMemsetAsync(csr_src + E, 0, (size_t)32 * 4, stream);  // zero pad records
    k_count<<<be, 256, 0, stream>>>(dst, E, count, rank);
    k_scan_part<8><<<nb, 256, 0, stream>>>(count, N, partial);
    k_scan_mid<<<1, 256, 0, stream>>>(partial, nb);
    k_scan_final<8><<<nb, 256, 0, stream>>>(count, N, partial, row_ptr, dis);
    k_fill<<<be, 256, 0, stream>>>(src, dst, E, rank, row_ptr, csr_src);

    // ---- layer 1: x[N,128] -> h[N,64] ----
    k_gemm_mfma<FIN1, 12, 4, HID><<<bg, 256, 0, stream>>>(
        x, wf1h, wf1l, dis, (unsigned short*)bufDD, (unsigned short*)bufCA,
        (unsigned short*)blkA, N);
    // s = ca + 2*P(cb): table out pre-scaled by dis[wid]
    k_prop<HID, 0><<<bp, 256, 0, stream>>>(row_ptr, csr_src, blkA, dis, bufCA,
                                           nullptr, nullptr, blkB, nullptr, N);
    // h = relu(dd + P(s) + b1): unscaled bf16 for GEMM2
    k_prop<HID, 1><<<bp, 256, 0, stream>>>(row_ptr, csr_src, blkB, dis, bufDD,
                                           nullptr, b1, buf4h, nullptr, N);

    // ---- layer 2: h[N,64] -> out[N,40] ----
    k_gemm_mfma_bf<HID, 8, 2, NCLS><<<bg, 256, 0, stream>>>(
        (const unsigned short*)buf4h, wf2h, wf2l, dis, buf0,
        (unsigned short*)bufDD, (unsigned short*)blkA, N);
    // s2 = da + 2*P(db)
    k_prop<NCLS, 0><<<bp, 256, 0, stream>>>(row_ptr, csr_src, blkA, dis, bufDD,
                                            nullptr, nullptr, blkB, nullptr, N);
    // out = log_softmax(dd2 + P(s2) + b2)
    k_prop<NCLS, 2><<<bp, 256, 0, stream>>>(row_ptr, csr_src, blkB, dis, nullptr,
                                            buf0, b2, nullptr, out, N);
}

// Round 11
// 330.029 us; speedup vs baseline: 1.5428x; 1.0662x over previous
//
#include <hip/hip_runtime.h>
#include <hip/hip_bf16.h>
#include <math.h>

// ---------------------------------------------------------------------------
// ChebNet (K=3) two-layer forward, restructured:
//   cheb(x,W) = x@(W0-W2) + P(x@W1 + 2*P(x@W2)) + b,  P = edge scatter-sum
// (W0-W2 folded at wprep). P applied in output feature space (64/40 dims).
// Edge scatter -> CSR-by-dst gather; 4B records (src only): gather tables
// pre-scaled by dis[src]; -dis[dst] factor is wave-uniform per node.
// k_count's atomicAdd return = within-dst rank -> k_fill is atomic-free.
// Count atomics: counters PADDED one per 64B line (16x less line serialization).
// k_count FUSED with GEMM1 (independent work, block-interleaved 4:1); GEMM1
// writes the cb-table unscaled, k_scale applies dis[r] after the scan.
// ---------------------------------------------------------------------------

#define FIN1 128
#define HID 64
#define NCLS 40
#define PAD 16  // counter padding: one counter per 64B line

typedef __attribute__((ext_vector_type(8))) short sx8;
typedef __attribute__((ext_vector_type(4))) float fx4;

__device__ inline unsigned short f2bf(float f) {
    unsigned u = __float_as_uint(f);
    unsigned r = (u + 0x7FFF + ((u >> 16) & 1)) >> 16;  // RNE
    return (unsigned short)r;
}
__device__ inline float bf2f(unsigned short h) {
    return __uint_as_float((unsigned)h << 16);
}
__device__ inline unsigned pack2bf(float a, float b) {
    return (unsigned)f2bf(a) | ((unsigned)f2bf(b) << 16);
}
__device__ inline float lo2f(unsigned v) { return __uint_as_float(v << 16); }
__device__ inline float hi2f(unsigned v) { return __uint_as_float(v & 0xffff0000u); }

// remainder-count fallback (only if 4*nG*256 < E)
__global__ void k_count_rem(const int* __restrict__ dst, int E, int e0,
                            int* __restrict__ count, int* __restrict__ rank) {
    int e = e0 + blockIdx.x * blockDim.x + threadIdx.x;
    if (e < E) rank[e] = atomicAdd(&count[dst[e] * PAD], 1);
}

// FUSED: block-interleaved count (4 of 5) + layer-1 MFMA GEMM (1 of 5).
// GEMM: fp32 A (hi/lo split, 3 MFMA), 16 rows/wave. Outputs (bf16, stride 64):
// OHd = x@(W0-W2), OHa = x@W1, Th = x@W2 (UNSCALED; k_scale applies dis later).
template <int FIN, int T, int NS, int FOE>
__global__ __launch_bounds__(256, 6) void k_count_gemm(
    const int* __restrict__ dst, int E, int* __restrict__ count,
    int* __restrict__ rank, const float* __restrict__ A,
    const unsigned short* __restrict__ Whi, const unsigned short* __restrict__ Wlo,
    unsigned short* __restrict__ OHd, unsigned short* __restrict__ OHa,
    unsigned short* __restrict__ Th, int N) {
    int b = blockIdx.x;
    int g = b / 5, r5 = b - g * 5;
    if (r5 != 4) {
        // ---- count role ----
        int e = (g * 4 + r5) * 256 + threadIdx.x;
        if (e < E) rank[e] = atomicAdd(&count[dst[e] * PAD], 1);
        return;
    }
    // ---- gemm role (block g) ----
    int tid = threadIdx.x;
    int w = tid >> 6, l = tid & 63;
    int row0 = g * 64 + w * 16;
    int rl = l & 15, kg = l >> 4;

    fx4 acc[T];
#pragma unroll
    for (int t = 0; t < T; ++t) acc[t] = (fx4)0.0f;

    for (int s = 0; s < NS; ++s) {
        int k0 = s * 32 + kg * 8;
        int r = min(row0 + rl, N - 1);
        const fx4* ap = (const fx4*)(A + (size_t)r * FIN + k0);
        fx4 a0 = ap[0];
        fx4 a1 = ap[1];
        sx8 ahi, alo;
#pragma unroll
        for (int j = 0; j < 4; ++j) {
            unsigned short h0 = f2bf(a0[j]);
            unsigned short h1 = f2bf(a1[j]);
            ahi[j] = (short)h0;
            ahi[j + 4] = (short)h1;
            alo[j] = (short)f2bf(a0[j] - bf2f(h0));
            alo[j + 4] = (short)f2bf(a1[j] - bf2f(h1));
        }
        const sx8* wh = (const sx8*)(Whi + ((size_t)(s * T) * 64 + l) * 8);
        const sx8* wl = (const sx8*)(Wlo + ((size_t)(s * T) * 64 + l) * 8);
#pragma unroll
        for (int t = 0; t < T; ++t) {
            sx8 bh = wh[t * 64];
            sx8 bl = wl[t * 64];
            acc[t] = __builtin_amdgcn_mfma_f32_16x16x32_bf16(ahi, bh, acc[t], 0, 0, 0);
            acc[t] = __builtin_amdgcn_mfma_f32_16x16x32_bf16(ahi, bl, acc[t], 0, 0, 0);
            acc[t] = __builtin_amdgcn_mfma_f32_16x16x32_bf16(alo, bh, acc[t], 0, 0, 0);
        }
    }

#pragma unroll
    for (int t = 0; t < T; ++t) {
        int col = t * 16 + rl;
        int m = col / FOE;
        int cc = col - m * FOE;
        if (m < 3) {
#pragma unroll
            for (int j = 0; j < 4; ++j) {
                int r = row0 + kg * 4 + j;
                if (r < N) {
                    if (m == 0) OHd[(size_t)r * 64 + cc] = f2bf(acc[t][j]);
                    else if (m == 1) OHa[(size_t)r * 64 + cc] = f2bf(acc[t][j]);
                    else Th[(size_t)r * 64 + cc] = f2bf(acc[t][j]);
                }
            }
        }
    }
}

// ---- hierarchical exclusive scan over padded count[N*PAD] ----
template <int EPT>
__global__ __launch_bounds__(256) void k_scan_part(const int* __restrict__ count, int N,
                                                   int* __restrict__ partial) {
    __shared__ int ws[4];
    int t = threadIdx.x;
    int lane = t & 63, w = t >> 6;
    int idx0 = blockIdx.x * 256 * EPT + t * EPT;
    int s = 0;
#pragma unroll
    for (int i = 0; i < EPT; ++i) {
        int idx = idx0 + i;
        if (idx < N) s += count[(size_t)idx * PAD];
    }
#pragma unroll
    for (int d = 1; d < 64; d <<= 1) s += __shfl_xor(s, d);
    if (lane == 0) ws[w] = s;
    __syncthreads();
    if (t == 0) partial[blockIdx.x] = ws[0] + ws[1] + ws[2] + ws[3];
}

__global__ __launch_bounds__(256) void k_scan_mid(int* __restrict__ partial, int nb) {
    __shared__ int s[256];
    int t = threadIdx.x;
    int orig = (t < nb) ? partial[t] : 0;
    s[t] = orig;
    __syncthreads();
    for (int d = 1; d < 256; d <<= 1) {
        int v = (t >= d) ? s[t - d] : 0;
        __syncthreads();
        s[t] += v;
        __syncthreads();
    }
    if (t < nb) partial[t] = s[t] - orig;  // exclusive
}

template <int EPT>
__global__ __launch_bounds__(256) void k_scan_final(const int* __restrict__ count, int N,
                                                    const int* __restrict__ partial,
                                                    int* __restrict__ row_ptr,
                                                    float* __restrict__ dis) {
    __shared__ int wsum[4];
    int t = threadIdx.x;
    int lane = t & 63, w = t >> 6;
    int idx0 = blockIdx.x * 256 * EPT + t * EPT;
    int c[EPT];
    int s = 0;
#pragma unroll
    for (int i = 0; i < EPT; ++i) {
        int idx = idx0 + i;
        c[i] = (idx < N) ? count[(size_t)idx * PAD] : 0;
        s += c[i];
    }
    int incl = s;
#pragma unroll
    for (int d = 1; d < 64; d <<= 1) {
        int u = __shfl_up(incl, d);
        if (lane >= d) incl += u;
    }
    if (lane == 63) wsum[w] = incl;
    __syncthreads();
    int woff = 0;
    for (int i = 0; i < w; ++i) woff += wsum[i];
    int off = partial[blockIdx.x] + woff + (incl - s);
#pragma unroll
    for (int i = 0; i < EPT; ++i) {
        int idx = idx0 + i;
        if (idx < N) {
            row_ptr[idx] = off;
            dis[idx] = (c[i] > 0) ? rsqrtf((float)c[i]) : 0.0f;
            off += c[i];
            if (idx == N - 1) row_ptr[N] = off;
        }
    }
}

// atomic-free fill: pos = row_ptr[dst] + rank
__global__ void k_fill(const int* __restrict__ src, const int* __restrict__ dst, int E,
                       const int* __restrict__ rank, const int* __restrict__ row_ptr,
                       unsigned* __restrict__ csr_src) {
    int e = blockIdx.x * blockDim.x + threadIdx.x;
    if (e < E) {
        int d = dst[e];
        csr_src[row_ptr[d] + rank[e]] = (unsigned)src[e];
    }
}

// scale table rows by dis[r] in place: tab is [N][32] packed bf16x2
__global__ void k_scale(unsigned* __restrict__ tab, const float* __restrict__ dis,
                        int N) {
    int i = blockIdx.x * 256 + threadIdx.x;  // uint4 index (8 per row)
    if (i >= N * 8) return;
    float d = dis[i >> 3];
    uint4 v = ((uint4*)tab)[i];
    v.x = pack2bf(d * lo2f(v.x), d * hi2f(v.x));
    v.y = pack2bf(d * lo2f(v.y), d * hi2f(v.y));
    v.z = pack2bf(d * lo2f(v.z), d * hi2f(v.z));
    v.w = pack2bf(d * lo2f(v.w), d * hi2f(v.w));
    ((uint4*)tab)[i] = v;
}

// Pre-swizzle into MFMA B-fragment layout, hi/lo bf16, with W0-W2 folding:
// logical matrix m: 0 -> W[0]-W[2], 1 -> W[1], 2 -> W[2].
template <int NS, int T, int FIN, int FOE>
__global__ void k_wprep(const float* __restrict__ W, unsigned short* __restrict__ hi,
                        unsigned short* __restrict__ lo) {
    int idx = blockIdx.x * 256 + threadIdx.x;
    constexpr int total = NS * T * 64 * 8;
    if (idx >= total) return;
    int i = idx & 7;
    int l = (idx >> 3) & 63;
    int t = (idx >> 9) % T;
    int s = idx / (512 * T);
    int k = s * 32 + (l >> 4) * 8 + i;
    int col = t * 16 + (l & 15);
    float w = 0.0f;
    if (col < 3 * FOE) {
        int m = col / FOE;
        int c = col - m * FOE;
        if (m == 0)
            w = W[((size_t)0 * FIN + k) * FOE + c] - W[((size_t)2 * FIN + k) * FOE + c];
        else
            w = W[((size_t)m * FIN + k) * FOE + c];
    }
    unsigned short h = f2bf(w);
    hi[idx] = h;
    lo[idx] = f2bf(w - bf2f(h));
}

// MFMA GEMM layer-2, bf16 A (exact, 2 MFMA), 16 rows/wave.
// Outputs: C0 = h@(W0-W2) fp32 (stride FOE, softmax input), OHa = h@W1 bf16,
// Th = dis[r] * (h@W2) bf16 table (ushort stride 64).
template <int FIN, int T, int NS, int FOE>
__global__ __launch_bounds__(256, 6) void k_gemm_mfma_bf(
    const unsigned short* __restrict__ A, const unsigned short* __restrict__ Whi,
    const unsigned short* __restrict__ Wlo, const float* __restrict__ dis,
    float* __restrict__ C0, unsigned short* __restrict__ OHa,
    unsigned short* __restrict__ Th, int N) {
    int tid = threadIdx.x;
    int w = tid >> 6, l = tid & 63;
    int row0 = blockIdx.x * 64 + w * 16;
    int rl = l & 15, kg = l >> 4;

    fx4 acc[T];
#pragma unroll
    for (int t = 0; t < T; ++t) acc[t] = (fx4)0.0f;

    for (int s = 0; s < NS; ++s) {
        int k0 = s * 32 + kg * 8;
        int r = min(row0 + rl, N - 1);
        sx8 a = *(const sx8*)(A + (size_t)r * FIN + k0);
        const sx8* wh = (const sx8*)(Whi + ((size_t)(s * T) * 64 + l) * 8);
        const sx8* wl = (const sx8*)(Wlo + ((size_t)(s * T) * 64 + l) * 8);
#pragma unroll
        for (int t = 0; t < T; ++t) {
            sx8 bh = wh[t * 64];
            sx8 bl = wl[t * 64];
            acc[t] = __builtin_amdgcn_mfma_f32_16x16x32_bf16(a, bh, acc[t], 0, 0, 0);
            acc[t] = __builtin_amdgcn_mfma_f32_16x16x32_bf16(a, bl, acc[t], 0, 0, 0);
        }
    }

    float ds_[4];
#pragma unroll
    for (int j = 0; j < 4; ++j) ds_[j] = dis[min(row0 + kg * 4 + j, N - 1)];

#pragma unroll
    for (int t = 0; t < T; ++t) {
        int col = t * 16 + rl;
        int m = col / FOE;
        int cc = col - m * FOE;
        if (m < 3) {
#pragma unroll
            for (int j = 0; j < 4; ++j) {
                int r = row0 + kg * 4 + j;
                if (r < N) {
                    if (m == 0) C0[(size_t)r * FOE + cc] = acc[t][j];
                    else if (m == 1) OHa[(size_t)r * 64 + cc] = f2bf(acc[t][j]);
                    else Th[(size_t)r * 64 + cc] = f2bf(ds_[j] * acc[t][j]);
                }
            }
        }
    }
}

// CSR gather-prop, dual-edge form, pre-scaled tables. One wave per dst node.
// Table rows: 32 dwords (64 bf16 feats), pre-scaled by dis[src]. Per-node
// factor -dis[wid] applied once in epilogue. 32-edge metadata chunks.
// MODE 0: outh = packbf16(dis[wid]*(oh - 2*dis[wid]*acc))   [table for next P]
// MODE 1: outh = packbf16(relu(oh - dis[wid]*acc + bias))   [oh = dd bf16]
// MODE 2: outf = log_softmax(o0f - dis[wid]*acc + bias) over F (o0f fp32)
template <int F, int MODE>
__global__ void k_prop(const int* __restrict__ row_ptr,
                       const unsigned* __restrict__ csr_src,
                       const unsigned* __restrict__ tab,
                       const float* __restrict__ dis,
                       const unsigned* __restrict__ oh,
                       const float* __restrict__ o0f,
                       const float* __restrict__ bias,
                       unsigned* __restrict__ outh, float* __restrict__ outf, int N) {
    constexpr int FH = F / 2;
    int wid = (blockIdx.x * blockDim.x + threadIdx.x) >> 6;
    int lane = threadIdx.x & 63;
    if (wid >= N) return;
    int g = lane >> 5;   // edge slot within a pair
    int c = lane & 31;   // feature-pair index
    int beg = row_ptr[wid];
    int end = row_ptr[wid + 1];
    float wd = dis[wid];
    float ax = 0.0f, ay = 0.0f;
    for (int j = beg; j < end; j += 32) {
        unsigned md = csr_src[j + (lane & 31)];  // 32-edge chunk, coalesced
#pragma unroll
        for (int t = 0; t < 16; ++t) {
            int idx = 2 * t + g;
            int s = __shfl((int)md, idx);
            unsigned v = tab[(size_t)s * 32 + c];
            v = (j + idx < end) ? v : 0u;
            ax += lo2f(v);
            ay += hi2f(v);
        }
    }
    ax += __shfl_xor(ax, 32);
    ay += __shfl_xor(ay, 32);

    if (MODE == 0) {
        if (g == 0 && c < FH) {
            unsigned ov = oh[(size_t)wid * 32 + c];
            float s0 = lo2f(ov) - 2.0f * wd * ax;
            float s1 = hi2f(ov) - 2.0f * wd * ay;
            outh[(size_t)wid * 32 + c] = pack2bf(wd * s0, wd * s1);
        }
    } else if (MODE == 1) {
        if (g == 0 && c < FH) {
            unsigned ov = oh[(size_t)wid * 32 + c];
            float2 b = ((const float2*)bias)[c];
            float z0 = fmaxf(lo2f(ov) - wd * ax + b.x, 0.0f);
            float z1 = fmaxf(hi2f(ov) - wd * ay + b.y, 0.0f);
            outh[(size_t)wid * 32 + c] = pack2bf(z0, z1);
        }
    } else {
        float z0 = -INFINITY, z1 = -INFINITY;
        if (g == 0 && c < FH) {
            float2 o = ((const float2*)o0f)[(size_t)wid * FH + c];
            float2 b = ((const float2*)bias)[c];
            z0 = o.x - wd * ax + b.x;
            z1 = o.y - wd * ay + b.y;
        }
        float m = fmaxf(z0, z1);
#pragma unroll
        for (int d = 32; d; d >>= 1) m = fmaxf(m, __shfl_xor(m, d));
        float e0 = (g == 0 && c < FH) ? expf(z0 - m) : 0.0f;
        float e1 = (g == 0 && c < FH) ? expf(z1 - m) : 0.0f;
        float l = e0 + e1;
#pragma unroll
        for (int d = 32; d; d >>= 1) l += __shfl_xor(l, d);
        if (g == 0 && c < FH) {
            float lg = m + logf(l);
            ((float2*)outf)[(size_t)wid * FH + c] = make_float2(z0 - lg, z1 - lg);
        }
    }
}

extern "C" void kernel_launch(void* const* d_in, const int* in_sizes, int n_in,
                              void* d_out, int out_size, void* d_ws, size_t ws_size,
                              hipStream_t stream) {
    const float* x = (const float*)d_in[0];
    const int* ei = (const int*)d_in[1];
    const float* W1 = (const float*)d_in[2];
    const float* b1 = (const float*)d_in[3];
    const float* W2 = (const float*)d_in[4];
    const float* b2 = (const float*)d_in[5];
    float* out = (float*)d_out;

    const int N = in_sizes[0] / FIN1;  // 100000
    const int E = in_sizes[1] / 2;     // 1600000
    const int* src = ei;
    const int* dst = ei + E;

    // workspace carve (256B aligned)
    char* p = (char*)d_ws;
    auto alloc = [&](size_t bytes) -> void* {
        void* r = (void*)p;
        p += (bytes + 255) & ~(size_t)255;
        return r;
    };
    int* count = (int*)alloc((size_t)N * PAD * 4);  // padded: 1 counter / 64B line
    int* row_ptr = (int*)alloc((size_t)(N + 1) * 4);
    float* dis = (float*)alloc((size_t)N * 4);
    int* partial = (int*)alloc(256 * 4);
    int* rank = (int*)alloc((size_t)E * 4);
    unsigned* csr_src = (unsigned*)alloc(((size_t)E + 32) * 4);  // 4B records + pad
    float* buf0 = (float*)alloc((size_t)N * NCLS * 4);      // dd2 fp32 (softmax in)
    unsigned* blkA = (unsigned*)alloc((size_t)N * 32 * 4);  // cb/db table (scaled)
    unsigned* blkB = (unsigned*)alloc((size_t)N * 32 * 4);  // s/s2 table (scaled)
    unsigned* bufDD = (unsigned*)alloc((size_t)N * 32 * 4); // dd1 bf16; then da
    unsigned* bufCA = (unsigned*)alloc((size_t)N * 32 * 4); // ca bf16
    unsigned* buf4h = (unsigned*)alloc((size_t)N * 32 * 4); // h bf16
    // W fragment buffers (hi/lo bf16, B-frag layout)
    constexpr int W1FRAG = 4 * 12 * 64 * 8;  // 24576
    constexpr int W2FRAG = 2 * 8 * 64 * 8;   // 8192
    unsigned short* wf1h = (unsigned short*)alloc((size_t)W1FRAG * 2);
    unsigned short* wf1l = (unsigned short*)alloc((size_t)W1FRAG * 2);
    unsigned short* wf2h = (unsigned short*)alloc((size_t)W2FRAG * 2);
    unsigned short* wf2l = (unsigned short*)alloc((size_t)W2FRAG * 2);

    const int be = (E + 255) / 256;
    const int bg = (N + 63) / 64;         // MFMA gemm blocks (64 rows/block)
    const int bp = (N * 64 + 255) / 256;  // one wave per node
    constexpr int EPB = 256 * 8;
    const int nb = (N + EPB - 1) / EPB;   // 49 blocks for N=100000

    // ---- W fragment prep (independent of graph) ----
    k_wprep<4, 12, FIN1, HID><<<(W1FRAG + 255) / 256, 256, 0, stream>>>(W1, wf1h, wf1l);
    k_wprep<2, 8, HID, NCLS><<<(W2FRAG + 255) / 256, 256, 0, stream>>>(W2, wf2h, wf2l);

    // ---- fused: degree count (+rank) interleaved with layer-1 GEMM ----
    hipMemsetAsync(count, 0, (size_t)N * PAD * 4, stream);
    hipMemsetAsync(csr_src + E, 0, (size_t)32 * 4, stream);  // zero pad records
    k_count_gemm<FIN1, 12, 4, HID><<<bg * 5, 256, 0, stream>>>(
        dst, E, count, rank, x, wf1h, wf1l, (unsigned short*)bufDD,
        (unsigned short*)bufCA, (unsigned short*)blkA, N);
    if (4 * bg * 256 < E) {  // remainder edges (not hit for this shape)
        int e0 = 4 * bg * 256;
        k_count_rem<<<(E - e0 + 255) / 256, 256, 0, stream>>>(dst, E, e0, count, rank);
    }

    // ---- row_ptr, dis; fill; scale cb-table by dis[r] ----
    k_scan_part<8><<<nb, 256, 0, stream>>>(count, N, partial);
    k_scan_mid<<<1, 256, 0, stream>>>(partial, nb);
    k_scan_final<8><<<nb, 256, 0, stream>>>(count, N, partial, row_ptr, dis);
    k_fill<<<be, 256, 0, stream>>>(src, dst, E, rank, row_ptr, csr_src);
    k_scale<<<(N * 8 + 255) / 256, 256, 0, stream>>>(blkA, dis, N);

    // ---- layer 1 props: x[N,128] -> h[N,64] ----
    // s = ca + 2*P(cb): table out pre-scaled by dis[wid]
    k_prop<HID, 0><<<bp, 256, 0, stream>>>(row_ptr, csr_src, blkA, dis, bufCA,
                                           nullptr, nullptr, blkB, nullptr, N);
    // h = relu(dd + P(s) + b1): unscaled bf16 for GEMM2
    k_prop<HID, 1><<<bp, 256, 0, stream>>>(row_ptr, csr_src, blkB, dis, bufDD,
                                           nullptr, b1, buf4h, nullptr, N);

    // ---- layer 2: h[N,64] -> out[N,40] ----
    k_gemm_mfma_bf<HID, 8, 2, NCLS><<<bg, 256, 0, stream>>>(
        (const unsigned short*)buf4h, wf2h, wf2l, dis, buf0,
        (unsigned short*)bufDD, (unsigned short*)blkA, N);
    // s2 = da + 2*P(db)
    k_prop<NCLS, 0><<<bp, 256, 0, stream>>>(row_ptr, csr_src, blkA, dis, bufDD,
                                            nullptr, nullptr, blkB, nullptr, N);
    // out = log_softmax(dd2 + P(s2) + b2)
    k_prop<NCLS, 2><<<bp, 256, 0, stream>>>(row_ptr, csr_src, blkB, dis, nullptr,
                                            buf0, b2, nullptr, out, N);
}